// Round 2
// baseline (623.034 us; speedup 1.0000x reference)
//
#include <hip/hip_runtime.h>
#include <hip/hip_bf16.h>
#include <math.h>

#define N_IN 85680
#define PRE_K 5000
#define POST_K 750
#define NW 79            // ceil(PRE_K/64) words
#define NPAD 5056        // NW*64
#define STR 80           // mask row stride in u64 (79 used, 1 pad)
#define HSIZE 16384      // histogram buckets on score bits[31:18]
#define CAND_MAX 8192
#define CONF_THR 0.02f
#define NMS_THR 0.4f

typedef unsigned int u32;
typedef unsigned long long u64;

// opacity barrier: prevents FMA contraction so f32 math bit-matches numpy ref
__device__ __forceinline__ float opaquef(float x) { asm volatile("" : "+v"(x)); return x; }

// ---------------- histogram of valid score bits ----------------
__global__ __launch_bounds__(256) void hist_kernel(const float* __restrict__ conf,
                                                   u32* __restrict__ hist) {
    __shared__ u32 h[HSIZE];
    for (int b = threadIdx.x; b < HSIZE; b += 256) h[b] = 0u;
    __syncthreads();
    int i = blockIdx.x * 256 + threadIdx.x;
    if (i < N_IN) {
        float s = conf[2 * i + 1];
        if (s > CONF_THR) atomicAdd(&h[__float_as_uint(s) >> 18], 1u);
    }
    __syncthreads();
    for (int b = threadIdx.x; b < HSIZE; b += 256) {
        u32 v = h[b];
        if (v) atomicAdd(&hist[b], v);
    }
}

// ---------------- find bucket threshold B: max b with suffix(b) >= PRE_K ----------------
__global__ __launch_bounds__(1024) void scan_kernel(const u32* __restrict__ hist,
                                                    u32* __restrict__ bsel) {
    __shared__ u32 tot[1024];
    int c = threadIdx.x;
    u32 lh[16];
    u32 t = 0;
#pragma unroll
    for (int k = 0; k < 16; ++k) { lh[k] = hist[c * 16 + k]; t += lh[k]; }
    tot[c] = t;
    __syncthreads();
    for (int d = 1; d < 1024; d <<= 1) {
        u32 v = tot[c] + ((c + d < 1024) ? tot[c + d] : 0u);
        __syncthreads();
        tot[c] = v;
        __syncthreads();
    }
    u32 above = (c + 1 < 1024) ? tot[c + 1] : 0u;  // suffix starting at next chunk
    if (above < PRE_K && above + t >= PRE_K) {     // boundary chunk (unique)
        u32 cum = above;
        for (int k = 15; k >= 0; --k) {
            cum += lh[k];
            if (cum >= PRE_K) { bsel[0] = (u32)(c * 16 + k); break; }
        }
    }
    if (c == 0 && tot[0] < PRE_K) bsel[0] = 0u;   // fewer than PRE_K valid: take all
}

// ---------------- compact candidates (bucket >= B) as sortable keys ----------------
__global__ __launch_bounds__(256) void compact_kernel(const float* __restrict__ conf,
                                                      const u32* __restrict__ bsel,
                                                      u32* __restrict__ counter,
                                                      u64* __restrict__ cand) {
    int i = blockIdx.x * 256 + threadIdx.x;
    if (i >= N_IN) return;
    float sc = conf[2 * i + 1];
    if (sc <= CONF_THR) return;
    u32 bits = __float_as_uint(sc);
    if ((bits >> 18) < bsel[0]) return;
    u32 pos = atomicAdd(counter, 1u);
    // key: high = score bits (positive floats are order-isomorphic to uint),
    // low = ~i so larger key == (higher score, then lower index)  == lax.top_k order
    if (pos < CAND_MAX) cand[pos] = ((u64)bits << 32) | (u64)(u32)(~(u32)i);
}

// ---------------- one-block bitonic sort of 8192 keys, emit top PRE_K descending ----------------
__global__ __launch_bounds__(1024) void sort_kernel(const u64* __restrict__ cand,
                                                    const u32* __restrict__ counter,
                                                    u64* __restrict__ topk) {
    __shared__ u64 s[CAND_MAX];
    u32 cnt = *counter;
    if (cnt > CAND_MAX) cnt = CAND_MAX;
    for (int t = threadIdx.x; t < CAND_MAX; t += 1024) s[t] = (t < (int)cnt) ? cand[t] : 0ull;
    __syncthreads();
    for (int k = 2; k <= CAND_MAX; k <<= 1) {
        for (int j = k >> 1; j > 0; j >>= 1) {
            for (int p = threadIdx.x; p < CAND_MAX / 2; p += 1024) {
                int i = ((p & ~(j - 1)) << 1) | (p & (j - 1));
                int l = i | j;
                bool up = ((i & k) == 0);
                u64 a = s[i], b = s[l];
                if ((a > b) == up) { s[i] = b; s[l] = a; }
            }
            __syncthreads();
        }
    }
    // ascending in s; top r-th (descending) = s[CAND_MAX-1-r]
    for (int r = threadIdx.x; r < PRE_K; r += 1024) topk[r] = s[CAND_MAX - 1 - r];
}

// ---------------- decode boxes + landmarks for the selected 5000 ----------------
__global__ __launch_bounds__(256) void decode_kernel(const u64* __restrict__ topk,
                                                     const float4* __restrict__ loc4,
                                                     const float4* __restrict__ pri4,
                                                     const float* __restrict__ lmk,
                                                     const int* __restrict__ imw,
                                                     const int* __restrict__ imh,
                                                     float* __restrict__ rows,
                                                     float4* __restrict__ boxes,
                                                     u64* __restrict__ validm) {
    int r = blockIdx.x * 256 + threadIdx.x;
    if (r >= PRE_K) return;
    u64 key = topk[r];
    float* row = rows + (size_t)r * 16;
    if (key == 0ull) {
        boxes[r] = make_float4(-3e30f, -3e30f, -3e30f, -3e30f);  // zero-area, far away
#pragma unroll
        for (int c = 0; c < 16; ++c) row[c] = 0.f;
        return;
    }
    u32 i = ~(u32)key;
    float score = __uint_as_float((u32)(key >> 32));
    float4 L = loc4[i];
    float4 P = pri4[i];
    float W = (float)(*imw), H = (float)(*imh);
    float cx = P.x + opaquef((L.x * 0.1f) * P.z);
    float cy = P.y + opaquef((L.y * 0.1f) * P.w);
    // exp in f64 then round: ~correctly-rounded f32 exp (closest to numpy)
    float bw = P.z * (float)exp((double)(L.z * 0.2f));
    float bh = P.w * (float)exp((double)(L.w * 0.2f));
    float hw = opaquef(bw * 0.5f), hh = opaquef(bh * 0.5f);
    float x0 = (cx - hw) * W, y0 = (cy - hh) * H;
    float x1 = (cx + hw) * W, y1 = (cy + hh) * H;
    boxes[r] = make_float4(x0, y0, x1, y1);
    row[0] = x0; row[1] = y0; row[2] = x1; row[3] = y1; row[4] = score;
#pragma unroll
    for (int p = 0; p < 5; ++p) {
        float2 lm = ((const float2*)lmk)[(size_t)i * 5 + p];
        float lx = (P.x + opaquef((lm.x * 0.1f) * P.z)) * W;
        float ly = (P.y + opaquef((lm.y * 0.1f) * P.w)) * H;
        row[5 + 2 * p] = lx;
        row[6 + 2 * p] = ly;
    }
    row[15] = 0.f;
    atomicOr(&validm[r >> 6], 1ull << (r & 63));
}

// ---------------- pairwise IoU suppression bitmask (upper triangle only) ----------------
__global__ __launch_bounds__(64) void mask_kernel(const float4* __restrict__ boxes,
                                                  u64* __restrict__ mask) {
    int rc = blockIdx.x, cc = blockIdx.y;
    if (cc < rc) return;  // lower-triangle words left unwritten (never consulted)
    __shared__ float4 cb[64];
    int t = threadIdx.x;
    cb[t] = boxes[cc * 64 + t];
    int i = rc * 64 + t;
    float4 bi = boxes[i];
    __syncthreads();
    float areai = (bi.z - bi.x) * (bi.w - bi.y);
    u64 word = 0ull;
    int jbase = cc * 64;
#pragma unroll 4
    for (int k = 0; k < 64; ++k) {
        float4 bj = cb[k];
        float areaj = (bj.z - bj.x) * (bj.w - bj.y);
        float ltx = fmaxf(bi.x, bj.x), lty = fmaxf(bi.y, bj.y);
        float rbx = fminf(bi.z, bj.z), rby = fminf(bi.w, bj.w);
        float wx = fmaxf(rbx - ltx, 0.f), wy = fmaxf(rby - lty, 0.f);
        float inter = opaquef(wx * wy);
        float uni = fmaxf(areai + areaj - inter, 1e-12f);
        float iou = inter / uni;
        if ((jbase + k) > i && iou > NMS_THR) word |= (1ull << k);
    }
    mask[(size_t)i * STR + cc] = word;
}

// ---------------- single-wave greedy NMS reduce (v2) ----------------
// Critical-path redesign:
//  - block-diagonal words preloaded to LDS; within-word suppression chain is
//    pure ffs+shfl+and on registers (no memory on the chain)
//  - cross-word suppression (row OR into remv) deferred to end-of-word,
//    issued as independent pipelined global loads (one latency per word)
//  - early exit once total kept >= POST_K (later keeps can't affect output:
//    their rank >= POST_K and suppression only removes later boxes)
__global__ __launch_bounds__(64) void reduce_kernel(const u64* __restrict__ mask,
                                                    const u64* __restrict__ validm,
                                                    u64* __restrict__ keepw,
                                                    u32* __restrict__ prefix) {
    int lane = threadIdx.x;
    __shared__ u64 diag[NW * 64];
    // preload diagonal words: row i's word (i>>6) — always written by mask_kernel (cc==rc kept)
    for (int i = lane; i < NW * 64; i += 64) {
        diag[i] = mask[(size_t)i * STR + (i >> 6)];
    }
    __syncthreads();

    u64 remv0 = 0ull, remv1 = 0ull, keep0 = 0ull, keep1 = 0ull;
    u64 valid0 = validm[lane];
    u64 valid1 = (lane < NW - 64) ? validm[64 + lane] : 0ull;
    u32 total = 0;

    for (int w = 0; w < NW; ++w) {
        u64 remw = (w < 64) ? __shfl(remv0, w) : __shfl(remv1, w - 64);
        u64 valw = (w < 64) ? __shfl(valid0, w) : __shfl(valid1, w - 64);
        u64 dreg = diag[(w << 6) + lane];  // lane b holds diag word of row w*64+b
        u64 cur = valw & ~remw;            // keep-candidates in this word
        u64 keptw = 0ull;
        while (cur) {
            int b = __ffsll((long long)cur) - 1;
            keptw |= (1ull << b);
            u64 roww = __shfl(dreg, b);    // same-word suppression bits of kept box
            cur &= ~(roww | (1ull << b));
        }
        if (w < 64) {
            if (lane == w) keep0 |= keptw;
        } else if (lane == w - 64) {
            keep1 |= keptw;
        }
        total += (u32)__popcll(keptw);     // keptw is wave-uniform
        if (total >= POST_K) break;        // output fully determined
        // deferred cross-word OR: pipelined independent loads, words > w only
        u64 k2 = keptw;
        while (k2) {
            int b = __ffsll((long long)k2) - 1;
            k2 &= k2 - 1;
            const u64* rowp = mask + (size_t)((w << 6) + b) * STR;
            if (lane > w) remv0 |= rowp[lane];
            if ((lane < NW - 64) && (64 + lane > w)) remv1 |= rowp[64 + lane];
        }
    }

    keepw[lane] = keep0;
    keepw[64 + lane] = keep1;
    __shared__ u32 pc[128];
    pc[lane] = (u32)__popcll(keep0);
    pc[64 + lane] = (u32)__popcll(keep1);
    __syncthreads();
    if (lane == 0) {
        u32 s = 0;
        for (int w = 0; w < NW; ++w) { prefix[w] = s; s += pc[w]; }
    }
}

// ---------------- scatter kept rows (rank < POST_K) ----------------
__global__ __launch_bounds__(256) void scatter_kernel(const float* __restrict__ rows,
                                                      const u64* __restrict__ keepw,
                                                      const u32* __restrict__ prefix,
                                                      float* __restrict__ out) {
    int r = blockIdx.x * 256 + threadIdx.x;
    if (r >= PRE_K) return;
    int w = r >> 6, b = r & 63;
    u64 kw = keepw[w];
    if (!((kw >> b) & 1ull)) return;
    u32 rank = prefix[w] + (u32)__popcll(kw & ((1ull << b) - 1ull));
    if (rank >= POST_K) return;
    const float* src = rows + (size_t)r * 16;
    float* dst = out + (size_t)rank * 15;
#pragma unroll
    for (int c = 0; c < 15; ++c) dst[c] = src[c];
}

extern "C" void kernel_launch(void* const* d_in, const int* in_sizes, int n_in,
                              void* d_out, int out_size, void* d_ws, size_t ws_size,
                              hipStream_t stream) {
    const float* loc = (const float*)d_in[0];
    const float* conf = (const float*)d_in[1];
    const float* lmk = (const float*)d_in[2];
    const float* pri = (const float*)d_in[3];
    const int* imw = (const int*)d_in[4];
    const int* imh = (const int*)d_in[5];
    float* out = (float*)d_out;
    char* base = (char*)d_ws;

    // workspace layout (bytes)
    u32* hist    = (u32*)(base + 0);        //  65536
    u32* counter = (u32*)(base + 65536);    //  64
    u32* bsel    = (u32*)(base + 65600);    //  64
    u64* validm  = (u64*)(base + 65664);    //  1024  (128 words)
    // zero region = [0, 66688)
    u64* keepw   = (u64*)(base + 66688);    //  1024  (128 words, fully written)
    u32* prefix  = (u32*)(base + 67712);    //  512
    u64* topk    = (u64*)(base + 68224);    //  40000
    u64* cand    = (u64*)(base + 108224);   //  65536
    float* rows  = (float*)(base + 173760); //  320000 (5000 x 16)
    float* boxes = (float*)(base + 493760); //  80896  (NPAD x 4)
    u64* mask    = (u64*)(base + 574656);   //  3235840 (NPAD x STR)  -> total ~3.64 MB

    hipMemsetAsync(d_ws, 0, 66688, stream);
    hipMemsetAsync(d_out, 0, (size_t)POST_K * 15 * sizeof(float), stream);

    hist_kernel<<<(N_IN + 255) / 256, 256, 0, stream>>>(conf, hist);
    scan_kernel<<<1, 1024, 0, stream>>>(hist, bsel);
    compact_kernel<<<(N_IN + 255) / 256, 256, 0, stream>>>(conf, bsel, counter, cand);
    sort_kernel<<<1, 1024, 0, stream>>>(cand, counter, topk);
    decode_kernel<<<(PRE_K + 255) / 256, 256, 0, stream>>>(topk, (const float4*)loc,
                                                           (const float4*)pri, lmk, imw, imh,
                                                           rows, (float4*)boxes, validm);
    mask_kernel<<<dim3(NW, NW), 64, 0, stream>>>((const float4*)boxes, mask);
    reduce_kernel<<<1, 64, 0, stream>>>(mask, validm, keepw, prefix);
    scatter_kernel<<<(PRE_K + 255) / 256, 256, 0, stream>>>(rows, keepw, prefix, out);
}

// Round 3
// 265.830 us; speedup vs baseline: 2.3437x; 2.3437x over previous
//
#include <hip/hip_runtime.h>
#include <hip/hip_bf16.h>
#include <math.h>

#define N_IN 85680
#define PRE_K 5000
#define POST_K 750
#define NW 79            // ceil(PRE_K/64) words
#define NPAD 5056        // NW*64
#define STR 80           // mask row stride in u64 (79 used, 1 pad)
#define HSIZE 16384      // histogram buckets on score bits[31:18]
#define CAND_MAX 8192
#define CONF_THR 0.02f
#define NMS_THR 0.4f

typedef unsigned int u32;
typedef unsigned long long u64;

// opacity barrier: prevents FMA contraction so f32 math bit-matches numpy ref
__device__ __forceinline__ float opaquef(float x) { asm volatile("" : "+v"(x)); return x; }

// wave-uniform 64-bit broadcast via v_readlane (src lane must be uniform)
__device__ __forceinline__ u64 readlane64(u64 v, int l) {
    u32 lo = __builtin_amdgcn_readlane((u32)v, l);
    u32 hi = __builtin_amdgcn_readlane((u32)(v >> 32), l);
    return ((u64)hi << 32) | (u64)lo;
}

// ---------------- histogram of valid score bits ----------------
__global__ __launch_bounds__(256) void hist_kernel(const float* __restrict__ conf,
                                                   u32* __restrict__ hist) {
    __shared__ u32 h[HSIZE];
    for (int b = threadIdx.x; b < HSIZE; b += 256) h[b] = 0u;
    __syncthreads();
    int i = blockIdx.x * 256 + threadIdx.x;
    if (i < N_IN) {
        float s = conf[2 * i + 1];
        if (s > CONF_THR) atomicAdd(&h[__float_as_uint(s) >> 18], 1u);
    }
    __syncthreads();
    for (int b = threadIdx.x; b < HSIZE; b += 256) {
        u32 v = h[b];
        if (v) atomicAdd(&hist[b], v);
    }
}

// ---------------- find bucket threshold B: max b with suffix(b) >= PRE_K ----------------
__global__ __launch_bounds__(1024) void scan_kernel(const u32* __restrict__ hist,
                                                    u32* __restrict__ bsel) {
    __shared__ u32 tot[1024];
    int c = threadIdx.x;
    u32 lh[16];
    u32 t = 0;
#pragma unroll
    for (int k = 0; k < 16; ++k) { lh[k] = hist[c * 16 + k]; t += lh[k]; }
    tot[c] = t;
    __syncthreads();
    for (int d = 1; d < 1024; d <<= 1) {
        u32 v = tot[c] + ((c + d < 1024) ? tot[c + d] : 0u);
        __syncthreads();
        tot[c] = v;
        __syncthreads();
    }
    u32 above = (c + 1 < 1024) ? tot[c + 1] : 0u;  // suffix starting at next chunk
    if (above < PRE_K && above + t >= PRE_K) {     // boundary chunk (unique)
        u32 cum = above;
        for (int k = 15; k >= 0; --k) {
            cum += lh[k];
            if (cum >= PRE_K) { bsel[0] = (u32)(c * 16 + k); break; }
        }
    }
    if (c == 0 && tot[0] < PRE_K) bsel[0] = 0u;   // fewer than PRE_K valid: take all
}

// ---------------- compact candidates (bucket >= B) as sortable keys ----------------
__global__ __launch_bounds__(256) void compact_kernel(const float* __restrict__ conf,
                                                      const u32* __restrict__ bsel,
                                                      u32* __restrict__ counter,
                                                      u64* __restrict__ cand) {
    int i = blockIdx.x * 256 + threadIdx.x;
    if (i >= N_IN) return;
    float sc = conf[2 * i + 1];
    if (sc <= CONF_THR) return;
    u32 bits = __float_as_uint(sc);
    if ((bits >> 18) < bsel[0]) return;
    u32 pos = atomicAdd(counter, 1u);
    // key: high = score bits (positive floats are order-isomorphic to uint),
    // low = ~i so larger key == (higher score, then lower index)  == lax.top_k order
    if (pos < CAND_MAX) cand[pos] = ((u64)bits << 32) | (u64)(u32)(~(u32)i);
}

// ---------------- one-block bitonic sort of 8192 keys, emit top PRE_K descending ----------------
__global__ __launch_bounds__(1024) void sort_kernel(const u64* __restrict__ cand,
                                                    const u32* __restrict__ counter,
                                                    u64* __restrict__ topk) {
    __shared__ u64 s[CAND_MAX];
    u32 cnt = *counter;
    if (cnt > CAND_MAX) cnt = CAND_MAX;
    for (int t = threadIdx.x; t < CAND_MAX; t += 1024) s[t] = (t < (int)cnt) ? cand[t] : 0ull;
    __syncthreads();
    for (int k = 2; k <= CAND_MAX; k <<= 1) {
        for (int j = k >> 1; j > 0; j >>= 1) {
            for (int p = threadIdx.x; p < CAND_MAX / 2; p += 1024) {
                int i = ((p & ~(j - 1)) << 1) | (p & (j - 1));
                int l = i | j;
                bool up = ((i & k) == 0);
                u64 a = s[i], b = s[l];
                if ((a > b) == up) { s[i] = b; s[l] = a; }
            }
            __syncthreads();
        }
    }
    // ascending in s; top r-th (descending) = s[CAND_MAX-1-r]
    for (int r = threadIdx.x; r < PRE_K; r += 1024) topk[r] = s[CAND_MAX - 1 - r];
}

// ---------------- decode boxes + landmarks for the selected 5000 ----------------
__global__ __launch_bounds__(256) void decode_kernel(const u64* __restrict__ topk,
                                                     const float4* __restrict__ loc4,
                                                     const float4* __restrict__ pri4,
                                                     const float* __restrict__ lmk,
                                                     const int* __restrict__ imw,
                                                     const int* __restrict__ imh,
                                                     float* __restrict__ rows,
                                                     float4* __restrict__ boxes,
                                                     u64* __restrict__ validm) {
    int r = blockIdx.x * 256 + threadIdx.x;
    if (r >= PRE_K) return;
    u64 key = topk[r];
    float* row = rows + (size_t)r * 16;
    if (key == 0ull) {
        boxes[r] = make_float4(-3e30f, -3e30f, -3e30f, -3e30f);  // zero-area, far away
#pragma unroll
        for (int c = 0; c < 16; ++c) row[c] = 0.f;
        return;
    }
    u32 i = ~(u32)key;
    float score = __uint_as_float((u32)(key >> 32));
    float4 L = loc4[i];
    float4 P = pri4[i];
    float W = (float)(*imw), H = (float)(*imh);
    float cx = P.x + opaquef((L.x * 0.1f) * P.z);
    float cy = P.y + opaquef((L.y * 0.1f) * P.w);
    // exp in f64 then round: ~correctly-rounded f32 exp (closest to numpy)
    float bw = P.z * (float)exp((double)(L.z * 0.2f));
    float bh = P.w * (float)exp((double)(L.w * 0.2f));
    float hw = opaquef(bw * 0.5f), hh = opaquef(bh * 0.5f);
    float x0 = (cx - hw) * W, y0 = (cy - hh) * H;
    float x1 = (cx + hw) * W, y1 = (cy + hh) * H;
    boxes[r] = make_float4(x0, y0, x1, y1);
    row[0] = x0; row[1] = y0; row[2] = x1; row[3] = y1; row[4] = score;
#pragma unroll
    for (int p = 0; p < 5; ++p) {
        float2 lm = ((const float2*)lmk)[(size_t)i * 5 + p];
        float lx = (P.x + opaquef((lm.x * 0.1f) * P.z)) * W;
        float ly = (P.y + opaquef((lm.y * 0.1f) * P.w)) * H;
        row[5 + 2 * p] = lx;
        row[6 + 2 * p] = ly;
    }
    row[15] = 0.f;
    atomicOr(&validm[r >> 6], 1ull << (r & 63));
}

// ---------------- pairwise IoU suppression bitmask (upper triangle only) ----------------
__global__ __launch_bounds__(64) void mask_kernel(const float4* __restrict__ boxes,
                                                  u64* __restrict__ mask,
                                                  u64* __restrict__ diagw) {
    int rc = blockIdx.x, cc = blockIdx.y;
    if (cc < rc) return;  // lower-triangle words left unwritten (never consulted)
    __shared__ float4 cb[64];
    int t = threadIdx.x;
    cb[t] = boxes[cc * 64 + t];
    int i = rc * 64 + t;
    float4 bi = boxes[i];
    __syncthreads();
    float areai = (bi.z - bi.x) * (bi.w - bi.y);
    u64 word = 0ull;
    int jbase = cc * 64;
#pragma unroll 4
    for (int k = 0; k < 64; ++k) {
        float4 bj = cb[k];
        float areaj = (bj.z - bj.x) * (bj.w - bj.y);
        float ltx = fmaxf(bi.x, bj.x), lty = fmaxf(bi.y, bj.y);
        float rbx = fminf(bi.z, bj.z), rby = fminf(bi.w, bj.w);
        float wx = fmaxf(rbx - ltx, 0.f), wy = fmaxf(rby - lty, 0.f);
        float inter = opaquef(wx * wy);
        float uni = fmaxf(areai + areaj - inter, 1e-12f);
        float iou = inter / uni;
        if ((jbase + k) > i && iou > NMS_THR) word |= (1ull << k);
    }
    mask[(size_t)i * STR + cc] = word;
    if (cc == rc) diagw[i] = word;   // compact contiguous diagonal for reduce preload
}

// ---------------- single-wave greedy NMS reduce (v3) ----------------
//  - within-word chain: LDS-preloaded diag words + v_readlane broadcast (no memory,
//    no ds_bpermute on the chain)
//  - cross-word OR: kept-row loads issued in explicit batches of 8 rows x 2 words,
//    16 independent loads -> ONE vmcnt wait per batch (not per kept box)
//  - early exit once total kept >= POST_K
__global__ __launch_bounds__(64) void reduce_kernel(const u64* __restrict__ mask,
                                                    const u64* __restrict__ diagw,
                                                    const u64* __restrict__ validm,
                                                    u64* __restrict__ keepw,
                                                    u32* __restrict__ prefix) {
    int lane = threadIdx.x;
    __shared__ u64 diag[NW * 64];
    for (int i = lane; i < NW * 64; i += 64) diag[i] = diagw[i];  // coalesced
    __syncthreads();

    u64 remv0 = 0ull, remv1 = 0ull, keep0 = 0ull, keep1 = 0ull;
    u64 valid0 = validm[lane];
    bool lo2 = (lane < NW - 64);
    u64 valid1 = lo2 ? validm[64 + lane] : 0ull;
    u32 total = 0;
    u64 dreg = diag[lane];  // word 0 diag

    for (int w = 0; w < NW; ++w) {
        u64 remw, valw;
        if (w < 64) { remw = readlane64(remv0, w); valw = readlane64(valid0, w); }
        else        { remw = readlane64(remv1, w - 64); valw = readlane64(valid1, w - 64); }
        u64 cur = valw & ~remw;            // keep-candidates in this word
        u64 keptw = 0ull;
        while (cur) {
            int b = __ffsll(cur) - 1;
            keptw |= (1ull << b);
            u64 roww = readlane64(dreg, b);  // same-word suppression bits (uniform b)
            cur &= ~(roww | (1ull << b));
        }
        if (w < 64) {
            if (lane == w) keep0 |= keptw;
        } else if (lane == w - 64) {
            keep1 |= keptw;
        }
        total += (u32)__popcll(keptw);     // keptw is wave-uniform
        if (total >= POST_K) break;        // output fully determined

        // prefetch next word's diag (latency hides under batch loads below)
        u64 dnext = (w + 1 < NW) ? diag[((w + 1) << 6) + lane] : 0ull;

        if (w + 1 < NW) {
            int base = w << 6;
            u64 k2 = keptw;
            while (k2) {
                // extract up to 8 kept indices (duplicates of b0 when fewer; OR idempotent)
                int b0 = __ffsll(k2) - 1;               k2 &= k2 - 1;
                int b1 = k2 ? __ffsll(k2) - 1 : b0;     k2 &= k2 - 1;
                int b2 = k2 ? __ffsll(k2) - 1 : b0;     k2 &= k2 - 1;
                int b3 = k2 ? __ffsll(k2) - 1 : b0;     k2 &= k2 - 1;
                int b4 = k2 ? __ffsll(k2) - 1 : b0;     k2 &= k2 - 1;
                int b5 = k2 ? __ffsll(k2) - 1 : b0;     k2 &= k2 - 1;
                int b6 = k2 ? __ffsll(k2) - 1 : b0;     k2 &= k2 - 1;
                int b7 = k2 ? __ffsll(k2) - 1 : b0;     k2 &= k2 - 1;
                const u64* r0 = mask + (size_t)(base + b0) * STR;
                const u64* r1 = mask + (size_t)(base + b1) * STR;
                const u64* r2 = mask + (size_t)(base + b2) * STR;
                const u64* r3 = mask + (size_t)(base + b3) * STR;
                const u64* r4 = mask + (size_t)(base + b4) * STR;
                const u64* r5 = mask + (size_t)(base + b5) * STR;
                const u64* r6 = mask + (size_t)(base + b6) * STR;
                const u64* r7 = mask + (size_t)(base + b7) * STR;
                // 8 independent loads, first half (stale columns <= w are never re-read,
                // so no lane guard needed)
                u64 a0 = r0[lane], a1 = r1[lane], a2 = r2[lane], a3 = r3[lane];
                u64 a4 = r4[lane], a5 = r5[lane], a6 = r6[lane], a7 = r7[lane];
                // 8 independent loads, second half (bounds-guarded: columns 64..78)
                u64 c0 = 0, c1 = 0, c2 = 0, c3 = 0, c4 = 0, c5 = 0, c6 = 0, c7 = 0;
                if (lo2) {
                    c0 = r0[64 + lane]; c1 = r1[64 + lane]; c2 = r2[64 + lane]; c3 = r3[64 + lane];
                    c4 = r4[64 + lane]; c5 = r5[64 + lane]; c6 = r6[64 + lane]; c7 = r7[64 + lane];
                }
                remv0 |= ((a0 | a1) | (a2 | a3)) | ((a4 | a5) | (a6 | a7));
                remv1 |= ((c0 | c1) | (c2 | c3)) | ((c4 | c5) | (c6 | c7));
            }
        }
        dreg = dnext;
    }

    keepw[lane] = keep0;
    keepw[64 + lane] = keep1;
    __shared__ u32 pc[128];
    pc[lane] = (u32)__popcll(keep0);
    pc[64 + lane] = (u32)__popcll(keep1);
    __syncthreads();
    if (lane == 0) {
        u32 s = 0;
        for (int w = 0; w < NW; ++w) { prefix[w] = s; s += pc[w]; }
    }
}

// ---------------- scatter kept rows (rank < POST_K) ----------------
__global__ __launch_bounds__(256) void scatter_kernel(const float* __restrict__ rows,
                                                      const u64* __restrict__ keepw,
                                                      const u32* __restrict__ prefix,
                                                      float* __restrict__ out) {
    int r = blockIdx.x * 256 + threadIdx.x;
    if (r >= PRE_K) return;
    int w = r >> 6, b = r & 63;
    u64 kw = keepw[w];
    if (!((kw >> b) & 1ull)) return;
    u32 rank = prefix[w] + (u32)__popcll(kw & ((1ull << b) - 1ull));
    if (rank >= POST_K) return;
    const float* src = rows + (size_t)r * 16;
    float* dst = out + (size_t)rank * 15;
#pragma unroll
    for (int c = 0; c < 15; ++c) dst[c] = src[c];
}

extern "C" void kernel_launch(void* const* d_in, const int* in_sizes, int n_in,
                              void* d_out, int out_size, void* d_ws, size_t ws_size,
                              hipStream_t stream) {
    const float* loc = (const float*)d_in[0];
    const float* conf = (const float*)d_in[1];
    const float* lmk = (const float*)d_in[2];
    const float* pri = (const float*)d_in[3];
    const int* imw = (const int*)d_in[4];
    const int* imh = (const int*)d_in[5];
    float* out = (float*)d_out;
    char* base = (char*)d_ws;

    // workspace layout (bytes)
    u32* hist    = (u32*)(base + 0);        //  65536 (dead after scan_kernel)
    u64* diagw   = (u64*)(base + 0);        //  40448 — overlaps hist: written by
                                            //  mask_kernel AFTER scan_kernel is done
    u32* counter = (u32*)(base + 65536);    //  64
    u32* bsel    = (u32*)(base + 65600);    //  64
    u64* validm  = (u64*)(base + 65664);    //  1024  (128 words)
    // zero region = [0, 66688)
    u64* keepw   = (u64*)(base + 66688);    //  1024  (128 words, fully written)
    u32* prefix  = (u32*)(base + 67712);    //  512
    u64* topk    = (u64*)(base + 68224);    //  40000
    u64* cand    = (u64*)(base + 108224);   //  65536
    float* rows  = (float*)(base + 173760); //  320000 (5000 x 16)
    float* boxes = (float*)(base + 493760); //  80896  (NPAD x 4)
    u64* mask    = (u64*)(base + 574656);   //  3235840 (NPAD x STR)  -> total ~3.64 MB

    hipMemsetAsync(d_ws, 0, 66688, stream);
    hipMemsetAsync(d_out, 0, (size_t)POST_K * 15 * sizeof(float), stream);

    hist_kernel<<<(N_IN + 255) / 256, 256, 0, stream>>>(conf, hist);
    scan_kernel<<<1, 1024, 0, stream>>>(hist, bsel);
    compact_kernel<<<(N_IN + 255) / 256, 256, 0, stream>>>(conf, bsel, counter, cand);
    sort_kernel<<<1, 1024, 0, stream>>>(cand, counter, topk);
    decode_kernel<<<(PRE_K + 255) / 256, 256, 0, stream>>>(topk, (const float4*)loc,
                                                           (const float4*)pri, lmk, imw, imh,
                                                           rows, (float4*)boxes, validm);
    mask_kernel<<<dim3(NW, NW), 64, 0, stream>>>((const float4*)boxes, mask, diagw);
    reduce_kernel<<<1, 64, 0, stream>>>(mask, diagw, validm, keepw, prefix);
    scatter_kernel<<<(PRE_K + 255) / 256, 256, 0, stream>>>(rows, keepw, prefix, out);
}

// Round 4
// 245.678 us; speedup vs baseline: 2.5360x; 1.0820x over previous
//
#include <hip/hip_runtime.h>
#include <hip/hip_bf16.h>
#include <math.h>

#define N_IN 85680
#define PRE_K 5000
#define POST_K 750
#define NW 79            // ceil(PRE_K/64) words
#define NPAD 5056        // NW*64
#define STR 80           // mask row stride in u64 (79 used, 1 pad)
#define HSIZE 16384      // linear buckets over score-bit range (0.02, +inf)
#define CAND_MAX 8192
#define CONF_THR 0.02f
#define NMS_THR 0.4f
#define CH 8             // words per reduce chunk
#define NCH ((NW + CH - 1) / CH)
#define BITS_THR 0x3CA3D70Bu  // bits of smallest float > 0.02f

typedef unsigned int u32;
typedef unsigned long long u64;

// opacity barrier: prevents FMA contraction so f32 math bit-matches numpy ref
__device__ __forceinline__ float opaquef(float x) { asm volatile("" : "+v"(x)); return x; }

// wave-uniform 64-bit broadcast via v_readlane (src lane must be uniform)
__device__ __forceinline__ u64 readlane64(u64 v, int l) {
    u32 lo = __builtin_amdgcn_readlane((u32)v, l);
    u32 hi = __builtin_amdgcn_readlane((u32)(v >> 32), l);
    return ((u64)hi << 32) | (u64)lo;
}

// monotone bucket of a score's float bits (score > CONF_THR guaranteed)
__device__ __forceinline__ u32 bucket_of(u32 bits) {
    u32 b = (bits - BITS_THR) >> 12;
    return b >= HSIZE ? (HSIZE - 1) : b;
}

// async global->LDS 16B (wave-uniform LDS base + lane*16)
__device__ __forceinline__ void gload_lds16(const void* g, void* l) {
    __builtin_amdgcn_global_load_lds(
        (const __attribute__((address_space(1))) void*)g,
        (__attribute__((address_space(3))) void*)l, 16, 0, 0);
}

// ---------------- histogram of valid score buckets ----------------
__global__ __launch_bounds__(256) void hist_kernel(const float2* __restrict__ conf2,
                                                   u32* __restrict__ hist) {
    __shared__ u32 h[HSIZE];
    for (int b = threadIdx.x; b < HSIZE; b += 256) h[b] = 0u;
    __syncthreads();
    int i = blockIdx.x * 256 + threadIdx.x;
    if (i < N_IN) {
        float s = conf2[i].y;
        if (s > CONF_THR) atomicAdd(&h[bucket_of(__float_as_uint(s))], 1u);
    }
    __syncthreads();
    for (int b = threadIdx.x; b < HSIZE; b += 256) {
        u32 v = h[b];
        if (v) atomicAdd(&hist[b], v);
    }
}

// ---------------- suffix-scan: bstart[b] = #keys in buckets > b; bsel ----------------
__global__ __launch_bounds__(1024) void scan_kernel(const u32* __restrict__ hist,
                                                    u32* __restrict__ bsel,
                                                    u32* __restrict__ bstart) {
    __shared__ u32 tot[1024];
    int c = threadIdx.x;
    u32 lh[16];
    u32 t = 0;
#pragma unroll
    for (int k = 0; k < 16; ++k) { lh[k] = hist[c * 16 + k]; t += lh[k]; }
    tot[c] = t;
    __syncthreads();
    for (int d = 1; d < 1024; d <<= 1) {
        u32 v = tot[c] + ((c + d < 1024) ? tot[c + d] : 0u);
        __syncthreads();
        tot[c] = v;
        __syncthreads();
    }
    u32 above = (c + 1 < 1024) ? tot[c + 1] : 0u;  // suffix starting at next chunk
    // exclusive suffix starts for this thread's 16 buckets
    u32 s = above;
    for (int k = 15; k >= 0; --k) { bstart[c * 16 + k] = s; s += lh[k]; }
    // bsel = max bucket with inclusive-suffix >= PRE_K (boundary thread unique)
    if (above < PRE_K && above + t >= PRE_K) {
        u32 cum = above;
        for (int k = 15; k >= 0; --k) {
            cum += lh[k];
            if (cum >= PRE_K) { bsel[0] = (u32)(c * 16 + k); break; }
        }
    }
    if (c == 0 && tot[0] < PRE_K) bsel[0] = 0u;   // fewer than PRE_K valid: take all
}

// ---------------- scatter candidates bucket-grouped ----------------
__global__ __launch_bounds__(256) void compact_kernel(const float2* __restrict__ conf2,
                                                      const u32* __restrict__ bsel,
                                                      const u32* __restrict__ bstart,
                                                      u32* __restrict__ bfill,
                                                      u64* __restrict__ cand) {
    int i = blockIdx.x * 256 + threadIdx.x;
    if (i >= N_IN) return;
    float sc = conf2[i].y;
    if (!(sc > CONF_THR)) return;
    u32 bits = __float_as_uint(sc);
    u32 b = bucket_of(bits);
    if (b < bsel[0]) return;
    u32 pos = bstart[b] + atomicAdd(&bfill[b], 1u);
    // key: high = score bits, low = ~i  (greater key == higher score, then lower index)
    if (pos < CAND_MAX) cand[pos] = ((u64)bits << 32) | (u64)(u32)(~(u32)i);
}

// ---------------- exact rank within bucket -> topk[rank] (replaces bitonic sort) ----------------
__global__ __launch_bounds__(256) void rank_kernel(const u64* __restrict__ cand,
                                                   const u32* __restrict__ bstart,
                                                   const u32* __restrict__ bfill,
                                                   const u32* __restrict__ bsel,
                                                   u64* __restrict__ topk) {
    u32 bs = bsel[0];
    u32 total = bstart[bs] + bfill[bs];
    if (total > CAND_MAX) total = CAND_MAX;
    for (u32 s = blockIdx.x * blockDim.x + threadIdx.x; s < total;
         s += gridDim.x * blockDim.x) {
        u64 key = cand[s];
        u32 b = bucket_of((u32)(key >> 32));
        u32 st = bstart[b];
        u32 en = st + bfill[b];
        if (en > CAND_MAX) en = CAND_MAX;
        u32 r = st;
        for (u32 j = st; j < en; ++j) r += (cand[j] > key) ? 1u : 0u;
        if (r < PRE_K) topk[r] = key;
    }
}

// ---------------- decode boxes + landmarks for the selected 5000 ----------------
__global__ __launch_bounds__(256) void decode_kernel(const u64* __restrict__ topk,
                                                     const float4* __restrict__ loc4,
                                                     const float4* __restrict__ pri4,
                                                     const float* __restrict__ lmk,
                                                     const int* __restrict__ imw,
                                                     const int* __restrict__ imh,
                                                     float4* __restrict__ rows4,
                                                     float4* __restrict__ boxes,
                                                     u64* __restrict__ validm) {
    int r = blockIdx.x * 256 + threadIdx.x;
    if (r >= PRE_K) return;
    u64 key = topk[r];
    float4* row = rows4 + (size_t)r * 4;
    if (key == 0ull) {
        float4 z = make_float4(0.f, 0.f, 0.f, 0.f);
        boxes[r] = make_float4(-3e30f, -3e30f, -3e30f, -3e30f);  // zero-area, far away
        row[0] = z; row[1] = z; row[2] = z; row[3] = z;
        return;
    }
    u32 i = ~(u32)key;
    float score = __uint_as_float((u32)(key >> 32));
    float4 L = loc4[i];
    float4 P = pri4[i];
    float W = (float)(*imw), H = (float)(*imh);
    float cx = P.x + opaquef((L.x * 0.1f) * P.z);
    float cy = P.y + opaquef((L.y * 0.1f) * P.w);
    // exp in f64 then round: ~correctly-rounded f32 exp (closest to numpy)
    float bw = P.z * (float)exp((double)(L.z * 0.2f));
    float bh = P.w * (float)exp((double)(L.w * 0.2f));
    float hw = opaquef(bw * 0.5f), hh = opaquef(bh * 0.5f);
    float x0 = (cx - hw) * W, y0 = (cy - hh) * H;
    float x1 = (cx + hw) * W, y1 = (cy + hh) * H;
    boxes[r] = make_float4(x0, y0, x1, y1);
    float lm[10];
#pragma unroll
    for (int p = 0; p < 5; ++p) {
        float2 q = ((const float2*)lmk)[(size_t)i * 5 + p];
        lm[2 * p]     = (P.x + opaquef((q.x * 0.1f) * P.z)) * W;
        lm[2 * p + 1] = (P.y + opaquef((q.y * 0.1f) * P.w)) * H;
    }
    row[0] = make_float4(x0, y0, x1, y1);
    row[1] = make_float4(score, lm[0], lm[1], lm[2]);
    row[2] = make_float4(lm[3], lm[4], lm[5], lm[6]);
    row[3] = make_float4(lm[7], lm[8], lm[9], 0.f);
    atomicOr(&validm[r >> 6], 1ull << (r & 63));
}

// ---------------- pairwise IoU suppression bitmask (upper triangle only) ----------------
__global__ __launch_bounds__(64) void mask_kernel(const float4* __restrict__ boxes,
                                                  u64* __restrict__ mask) {
    int rc = blockIdx.x, cc = blockIdx.y;
    if (cc < rc) return;  // lower-triangle words left unwritten (never consulted)
    __shared__ float4 cb[64];
    int t = threadIdx.x;
    cb[t] = boxes[cc * 64 + t];
    int i = rc * 64 + t;
    float4 bi = boxes[i];
    __syncthreads();
    float areai = (bi.z - bi.x) * (bi.w - bi.y);
    u64 word = 0ull;
    int jbase = cc * 64;
#pragma unroll 4
    for (int k = 0; k < 64; ++k) {
        float4 bj = cb[k];
        float areaj = (bj.z - bj.x) * (bj.w - bj.y);
        float ltx = fmaxf(bi.x, bj.x), lty = fmaxf(bi.y, bj.y);
        float rbx = fminf(bi.z, bj.z), rby = fminf(bi.w, bj.w);
        float wx = fmaxf(rbx - ltx, 0.f), wy = fmaxf(rby - lty, 0.f);
        float inter = opaquef(wx * wy);
        float uni = fmaxf(areai + areaj - inter, 1e-12f);
        float iou = inter / uni;
        if ((jbase + k) > i && iou > NMS_THR) word |= (1ull << k);
    }
    mask[(size_t)i * STR + cc] = word;
}

// swizzled LDS tile read: (local row r, within-chunk word wl)
#define TILE_RD(r, wl) tile[(size_t)(r) * CH + ((((u32)(wl) >> 1) ^ ((r) & 3)) << 1) + ((wl) & 1)]

// ---------------- single-wave greedy NMS reduce (v4: chunked) ----------------
//  - per chunk of 8 words (512 boxes): stage 512x8 u64 sub-matrix to LDS via
//    global_load_lds (16B, swizzled); all within-chunk suppression from LDS
//  - cross-chunk propagation batched at end of chunk (pipelined global loads)
//  - early exit once total kept >= POST_K
__global__ __launch_bounds__(64) void reduce_kernel(const u64* __restrict__ mask,
                                                    const u64* __restrict__ validm,
                                                    u64* __restrict__ keepw,
                                                    u32* __restrict__ prefix) {
    int lane = threadIdx.x;
    __shared__ __align__(16) u64 tile[CH * 64 * CH];  // [512 rows][8 words], 32 KiB

    u64 remv0 = 0ull, remv1 = 0ull, keep0 = 0ull, keep1 = 0ull;
    u64 valid0 = validm[lane];
    bool lo2 = (lane < NW - 64);
    u64 valid1 = lo2 ? validm[64 + lane] : 0ull;
    u32 total = 0;

    for (int c = 0; c < NCH; ++c) {
        int cbase = c * CH;
        int cend = cbase + CH; if (cend > NW) cend = NW;
        int rowbase = cbase * 64;
        bool c8 = (c < 8);

        __syncthreads();  // fence previous chunk's tile reads vs DMA overwrite
        // stage tile: dest slot p (16B) of row r holds source column-pair p^(r&3)
        int srcpair = (lane & 3) ^ ((lane >> 2) & 3);
#pragma unroll
        for (int it = 0; it < 32; ++it) {
            int r = it * 16 + (lane >> 2);
            int grow = rowbase + r; if (grow > NPAD - 1) grow = NPAD - 1;  // clamp tail (unused rows)
            const void* g = (const void*)(mask + (size_t)grow * STR + cbase + srcpair * 2);
            void* l = (void*)((char*)tile + (size_t)it * 1024 + lane * 16);
            gload_lds16(g, l);
        }
        asm volatile("s_waitcnt vmcnt(0)" ::: "memory");
        __syncthreads();

        u64 kw[CH] = {0, 0, 0, 0, 0, 0, 0, 0};
        int wordofl = c8 ? lane : 64 + lane;  // global word this lane's remv bit-column holds
        int wp = wordofl - cbase;             // lane's within-chunk word index

#pragma unroll
        for (int wloc = 0; wloc < CH; ++wloc) {
            int w = cbase + wloc;
            if (w >= NW) break;
            u64 remw, valw;
            if (c8) { remw = readlane64(remv0, w);       valw = readlane64(valid0, w); }
            else    { remw = readlane64(remv1, w - 64);  valw = readlane64(valid1, w - 64); }
            int dr = (wloc << 6) + lane;      // lane b holds diag word of row w*64+b
            u64 dreg = TILE_RD(dr, wloc);
            u64 cur = valw & ~remw;
            u64 keptw = 0ull;
            while (cur) {                     // cur is wave-uniform
                int b = __ffsll(cur) - 1;
                keptw |= (1ull << b);
                u64 roww = readlane64(dreg, b);
                cur &= ~(roww | (1ull << b));
            }
            kw[wloc] = keptw;
            if (c8) { if (lane == w) keep0 |= keptw; }
            else if (lane == w - 64) keep1 |= keptw;
            total += (u32)__popcll(keptw);
            if (total >= POST_K) goto done;   // output fully determined
            // within-chunk suppression to later words (LDS, batch of 4)
            if (keptw && wloc < CH - 1) {
                bool act = (wp > wloc) && (wordofl < cend);
                int rb = wloc << 6;
                u64 k2 = keptw;
                while (k2) {
                    int b0 = __ffsll(k2) - 1;            k2 &= k2 - 1;
                    int b1 = k2 ? __ffsll(k2) - 1 : b0;  k2 &= k2 - 1;
                    int b2 = k2 ? __ffsll(k2) - 1 : b0;  k2 &= k2 - 1;
                    int b3 = k2 ? __ffsll(k2) - 1 : b0;  k2 &= k2 - 1;
                    if (act) {
                        u64 t0 = TILE_RD(rb + b0, wp);
                        u64 t1 = TILE_RD(rb + b1, wp);
                        u64 t2 = TILE_RD(rb + b2, wp);
                        u64 t3 = TILE_RD(rb + b3, wp);
                        u64 acc = (t0 | t1) | (t2 | t3);
                        if (c8) remv0 |= acc; else remv1 |= acc;
                    }
                }
            }
        }

        // end-of-chunk global propagation to future chunks (pipelined batches of 8)
        if (cend < NW) {
#pragma unroll
            for (int wloc = 0; wloc < CH; ++wloc) {
                u64 k2 = kw[wloc];
                int base = (cbase + wloc) << 6;
                while (k2) {
                    int b0 = __ffsll(k2) - 1;            k2 &= k2 - 1;
                    int b1 = k2 ? __ffsll(k2) - 1 : b0;  k2 &= k2 - 1;
                    int b2 = k2 ? __ffsll(k2) - 1 : b0;  k2 &= k2 - 1;
                    int b3 = k2 ? __ffsll(k2) - 1 : b0;  k2 &= k2 - 1;
                    int b4 = k2 ? __ffsll(k2) - 1 : b0;  k2 &= k2 - 1;
                    int b5 = k2 ? __ffsll(k2) - 1 : b0;  k2 &= k2 - 1;
                    int b6 = k2 ? __ffsll(k2) - 1 : b0;  k2 &= k2 - 1;
                    int b7 = k2 ? __ffsll(k2) - 1 : b0;  k2 &= k2 - 1;
                    const u64* r0 = mask + (size_t)(base + b0) * STR;
                    const u64* r1 = mask + (size_t)(base + b1) * STR;
                    const u64* r2 = mask + (size_t)(base + b2) * STR;
                    const u64* r3 = mask + (size_t)(base + b3) * STR;
                    const u64* r4 = mask + (size_t)(base + b4) * STR;
                    const u64* r5 = mask + (size_t)(base + b5) * STR;
                    const u64* r6 = mask + (size_t)(base + b6) * STR;
                    const u64* r7 = mask + (size_t)(base + b7) * STR;
                    if (c8) {  // stale-OK: processed columns never re-read
                        u64 a0 = r0[lane], a1 = r1[lane], a2 = r2[lane], a3 = r3[lane];
                        u64 a4 = r4[lane], a5 = r5[lane], a6 = r6[lane], a7 = r7[lane];
                        remv0 |= ((a0 | a1) | (a2 | a3)) | ((a4 | a5) | (a6 | a7));
                    }
                    if (lo2) {
                        u64 d0 = r0[64 + lane], d1 = r1[64 + lane], d2 = r2[64 + lane], d3 = r3[64 + lane];
                        u64 d4 = r4[64 + lane], d5 = r5[64 + lane], d6 = r6[64 + lane], d7 = r7[64 + lane];
                        remv1 |= ((d0 | d1) | (d2 | d3)) | ((d4 | d5) | (d6 | d7));
                    }
                }
            }
        }
    }
done:
    keepw[lane] = keep0;
    keepw[64 + lane] = keep1;
    __shared__ u32 pc[128];
    pc[lane] = (u32)__popcll(keep0);
    pc[64 + lane] = (u32)__popcll(keep1);
    __syncthreads();
    if (lane == 0) {
        u32 s = 0;
        for (int w = 0; w < NW; ++w) { prefix[w] = s; s += pc[w]; }
    }
}

// ---------------- scatter kept rows (rank < POST_K) ----------------
__global__ __launch_bounds__(256) void scatter_kernel(const float* __restrict__ rows,
                                                      const u64* __restrict__ keepw,
                                                      const u32* __restrict__ prefix,
                                                      float* __restrict__ out) {
    int r = blockIdx.x * 256 + threadIdx.x;
    if (r >= PRE_K) return;
    int w = r >> 6, b = r & 63;
    u64 kw = keepw[w];
    if (!((kw >> b) & 1ull)) return;
    u32 rank = prefix[w] + (u32)__popcll(kw & ((1ull << b) - 1ull));
    if (rank >= POST_K) return;
    const float* src = rows + (size_t)r * 16;
    float* dst = out + (size_t)rank * 15;
#pragma unroll
    for (int c = 0; c < 15; ++c) dst[c] = src[c];
}

extern "C" void kernel_launch(void* const* d_in, const int* in_sizes, int n_in,
                              void* d_out, int out_size, void* d_ws, size_t ws_size,
                              hipStream_t stream) {
    const float* loc = (const float*)d_in[0];
    const float2* conf2 = (const float2*)d_in[1];
    const float* lmk = (const float*)d_in[2];
    const float* pri = (const float*)d_in[3];
    const int* imw = (const int*)d_in[4];
    const int* imh = (const int*)d_in[5];
    float* out = (float*)d_out;
    char* base = (char*)d_ws;

    // workspace layout (bytes); total 3808896 (< 3.81 MB proven in R1-R3)
    u32* hist   = (u32*)(base + 0);         //  65536  [zeroed]
    u32* bfill  = (u32*)(base + 65536);     //  65536  [zeroed]
    u32* bsel   = (u32*)(base + 131072);    //  64     [zeroed]
    u64* validm = (u64*)(base + 131136);    //  1024   [zeroed]
    u64* topk   = (u64*)(base + 132160);    //  40000  [zeroed] -> 172160
    u32* bstart = (u32*)(base + 172160);    //  65536  -> 237696
    u64* cand   = (u64*)(base + 237696);    //  65536  -> 303232
    // rows OVERLAPS bstart+cand: those are dead once rank_kernel completes,
    // and decode_kernel (writer of rows) runs strictly after rank_kernel.
    float* rows = (float*)(base + 172160);  //  320000 -> 492160
    float4* boxes = (float4*)(base + 492160); // 80896 -> 573056
    // keepw/prefix OVERLAP boxes: boxes dead after mask_kernel; reduce writes later.
    u64* keepw  = (u64*)(base + 492160);    //  1024
    u32* prefix = (u32*)(base + 493184);    //  512
    u64* mask   = (u64*)(base + 573056);    //  3235840 -> 3808896

    hipMemsetAsync(d_ws, 0, 172160, stream);
    hipMemsetAsync(d_out, 0, (size_t)POST_K * 15 * sizeof(float), stream);

    hist_kernel<<<(N_IN + 255) / 256, 256, 0, stream>>>(conf2, hist);
    scan_kernel<<<1, 1024, 0, stream>>>(hist, bsel, bstart);
    compact_kernel<<<(N_IN + 255) / 256, 256, 0, stream>>>(conf2, bsel, bstart, bfill, cand);
    rank_kernel<<<24, 256, 0, stream>>>(cand, bstart, bfill, bsel, topk);
    decode_kernel<<<(PRE_K + 255) / 256, 256, 0, stream>>>(topk, (const float4*)loc,
                                                           (const float4*)pri, lmk, imw, imh,
                                                           (float4*)rows, boxes, validm);
    mask_kernel<<<dim3(NW, NW), 64, 0, stream>>>(boxes, mask);
    reduce_kernel<<<1, 64, 0, stream>>>(mask, validm, keepw, prefix);
    scatter_kernel<<<(PRE_K + 255) / 256, 256, 0, stream>>>(rows, keepw, prefix, out);
}

// Round 5
// 180.818 us; speedup vs baseline: 3.4457x; 1.3587x over previous
//
#include <hip/hip_runtime.h>
#include <hip/hip_bf16.h>
#include <math.h>

#define N_IN 85680
#define PRE_K 5000
#define POST_K 750
#define NW 79            // ceil(PRE_K/64) words
#define NPAD 5056        // NW*64
#define STR 80           // mask row stride in u64 (79 used, 1 pad)
#define HSIZE 16384      // linear buckets over score-bit range (0.02, +inf)
#define CAND_MAX 8192
#define CONF_THR 0.02f
#define NMS_THR 0.4f
#define BITS_THR 0x3CA3D70Bu  // bits of smallest float > 0.02f
#define NSLOT 63         // LDS row slots for propagation (63 KB)

typedef unsigned int u32;
typedef unsigned long long u64;

// opacity barrier: prevents FMA contraction so f32 math bit-matches numpy ref
__device__ __forceinline__ float opaquef(float x) { asm volatile("" : "+v"(x)); return x; }

// wave-uniform 64-bit broadcast via v_readlane (src lane must be uniform)
__device__ __forceinline__ u64 readlane64(u64 v, int l) {
    u32 lo = __builtin_amdgcn_readlane((u32)v, l);
    u32 hi = __builtin_amdgcn_readlane((u32)(v >> 32), l);
    return ((u64)hi << 32) | (u64)lo;
}

// monotone bucket of a score's float bits (score > CONF_THR guaranteed)
__device__ __forceinline__ u32 bucket_of(u32 bits) {
    u32 b = (bits - BITS_THR) >> 12;
    return b >= HSIZE ? (HSIZE - 1) : b;
}

// async global->LDS 16B: global src is PER-LANE, LDS dest is wave-uniform base
// (HW writes base + lane*16)
__device__ __forceinline__ void gload_lds16(const void* g, void* l) {
    __builtin_amdgcn_global_load_lds(
        (const __attribute__((address_space(1))) void*)g,
        (__attribute__((address_space(3))) void*)l, 16, 0, 0);
}

// ---------------- histogram of valid score buckets ----------------
__global__ __launch_bounds__(256) void hist_kernel(const float2* __restrict__ conf2,
                                                   u32* __restrict__ hist) {
    __shared__ u32 h[HSIZE];
    for (int b = threadIdx.x; b < HSIZE; b += 256) h[b] = 0u;
    __syncthreads();
    int i = blockIdx.x * 256 + threadIdx.x;
    if (i < N_IN) {
        float s = conf2[i].y;
        if (s > CONF_THR) atomicAdd(&h[bucket_of(__float_as_uint(s))], 1u);
    }
    __syncthreads();
    for (int b = threadIdx.x; b < HSIZE; b += 256) {
        u32 v = h[b];
        if (v) atomicAdd(&hist[b], v);
    }
}

// ---------------- suffix-scan: bstart[b] = #keys in buckets > b; bsel ----------------
__global__ __launch_bounds__(1024) void scan_kernel(const u32* __restrict__ hist,
                                                    u32* __restrict__ bsel,
                                                    u32* __restrict__ bstart) {
    __shared__ u32 tot[1024];
    int c = threadIdx.x;
    u32 lh[16];
    u32 t = 0;
#pragma unroll
    for (int k = 0; k < 16; ++k) { lh[k] = hist[c * 16 + k]; t += lh[k]; }
    tot[c] = t;
    __syncthreads();
    for (int d = 1; d < 1024; d <<= 1) {
        u32 v = tot[c] + ((c + d < 1024) ? tot[c + d] : 0u);
        __syncthreads();
        tot[c] = v;
        __syncthreads();
    }
    u32 above = (c + 1 < 1024) ? tot[c + 1] : 0u;  // suffix starting at next chunk
    // exclusive suffix starts for this thread's 16 buckets
    u32 s = above;
    for (int k = 15; k >= 0; --k) { bstart[c * 16 + k] = s; s += lh[k]; }
    // bsel = max bucket with inclusive-suffix >= PRE_K (boundary thread unique)
    if (above < PRE_K && above + t >= PRE_K) {
        u32 cum = above;
        for (int k = 15; k >= 0; --k) {
            cum += lh[k];
            if (cum >= PRE_K) { bsel[0] = (u32)(c * 16 + k); break; }
        }
    }
    if (c == 0 && tot[0] < PRE_K) bsel[0] = 0u;   // fewer than PRE_K valid: take all
}

// ---------------- scatter candidates bucket-grouped ----------------
__global__ __launch_bounds__(256) void compact_kernel(const float2* __restrict__ conf2,
                                                      const u32* __restrict__ bsel,
                                                      const u32* __restrict__ bstart,
                                                      u32* __restrict__ bfill,
                                                      u64* __restrict__ cand) {
    int i = blockIdx.x * 256 + threadIdx.x;
    if (i >= N_IN) return;
    float sc = conf2[i].y;
    if (!(sc > CONF_THR)) return;
    u32 bits = __float_as_uint(sc);
    u32 b = bucket_of(bits);
    if (b < bsel[0]) return;
    u32 pos = bstart[b] + atomicAdd(&bfill[b], 1u);
    // key: high = score bits, low = ~i  (greater key == higher score, then lower index)
    if (pos < CAND_MAX) cand[pos] = ((u64)bits << 32) | (u64)(u32)(~(u32)i);
}

// ---------------- exact rank within bucket -> topk[rank] ----------------
__global__ __launch_bounds__(256) void rank_kernel(const u64* __restrict__ cand,
                                                   const u32* __restrict__ bstart,
                                                   const u32* __restrict__ bfill,
                                                   const u32* __restrict__ bsel,
                                                   u64* __restrict__ topk) {
    u32 bs = bsel[0];
    u32 total = bstart[bs] + bfill[bs];
    if (total > CAND_MAX) total = CAND_MAX;
    for (u32 s = blockIdx.x * blockDim.x + threadIdx.x; s < total;
         s += gridDim.x * blockDim.x) {
        u64 key = cand[s];
        u32 b = bucket_of((u32)(key >> 32));
        u32 st = bstart[b];
        u32 en = st + bfill[b];
        if (en > CAND_MAX) en = CAND_MAX;
        u32 r = st;
        for (u32 j = st; j < en; ++j) r += (cand[j] > key) ? 1u : 0u;
        if (r < PRE_K) topk[r] = key;
    }
}

// ---------------- decode boxes + landmarks for the selected 5000 ----------------
__global__ __launch_bounds__(256) void decode_kernel(const u64* __restrict__ topk,
                                                     const float4* __restrict__ loc4,
                                                     const float4* __restrict__ pri4,
                                                     const float* __restrict__ lmk,
                                                     const int* __restrict__ imw,
                                                     const int* __restrict__ imh,
                                                     float4* __restrict__ rows4,
                                                     float4* __restrict__ boxes,
                                                     u64* __restrict__ validm) {
    int r = blockIdx.x * 256 + threadIdx.x;
    if (r >= PRE_K) return;
    u64 key = topk[r];
    float4* row = rows4 + (size_t)r * 4;
    if (key == 0ull) {
        float4 z = make_float4(0.f, 0.f, 0.f, 0.f);
        boxes[r] = make_float4(-3e30f, -3e30f, -3e30f, -3e30f);  // zero-area, far away
        row[0] = z; row[1] = z; row[2] = z; row[3] = z;
        return;
    }
    u32 i = ~(u32)key;
    float score = __uint_as_float((u32)(key >> 32));
    float4 L = loc4[i];
    float4 P = pri4[i];
    float W = (float)(*imw), H = (float)(*imh);
    float cx = P.x + opaquef((L.x * 0.1f) * P.z);
    float cy = P.y + opaquef((L.y * 0.1f) * P.w);
    // exp in f64 then round: ~correctly-rounded f32 exp (closest to numpy)
    float bw = P.z * (float)exp((double)(L.z * 0.2f));
    float bh = P.w * (float)exp((double)(L.w * 0.2f));
    float hw = opaquef(bw * 0.5f), hh = opaquef(bh * 0.5f);
    float x0 = (cx - hw) * W, y0 = (cy - hh) * H;
    float x1 = (cx + hw) * W, y1 = (cy + hh) * H;
    boxes[r] = make_float4(x0, y0, x1, y1);
    float lm[10];
#pragma unroll
    for (int p = 0; p < 5; ++p) {
        float2 q = ((const float2*)lmk)[(size_t)i * 5 + p];
        lm[2 * p]     = (P.x + opaquef((q.x * 0.1f) * P.z)) * W;
        lm[2 * p + 1] = (P.y + opaquef((q.y * 0.1f) * P.w)) * H;
    }
    row[0] = make_float4(x0, y0, x1, y1);
    row[1] = make_float4(score, lm[0], lm[1], lm[2]);
    row[2] = make_float4(lm[3], lm[4], lm[5], lm[6]);
    row[3] = make_float4(lm[7], lm[8], lm[9], 0.f);
    atomicOr(&validm[r >> 6], 1ull << (r & 63));
}

// ---------------- pairwise IoU suppression bitmask (flat triangular grid) ----------------
__global__ __launch_bounds__(64) void mask_kernel(const float4* __restrict__ boxes,
                                                  u64* __restrict__ mask) {
    // flat bid -> (rc, cc) with cc >= rc; row rc owns NW-rc blocks
    int rem = blockIdx.x, rc = 0;
    while (rem >= NW - rc) { rem -= NW - rc; ++rc; }
    int cc = rc + rem;
    __shared__ float4 cb[64];
    int t = threadIdx.x;
    cb[t] = boxes[cc * 64 + t];
    int i = rc * 64 + t;
    float4 bi = boxes[i];
    __syncthreads();
    float areai = (bi.z - bi.x) * (bi.w - bi.y);
    u64 word = 0ull;
    int jbase = cc * 64;
#pragma unroll 4
    for (int k = 0; k < 64; ++k) {
        float4 bj = cb[k];
        float areaj = (bj.z - bj.x) * (bj.w - bj.y);
        float ltx = fmaxf(bi.x, bj.x), lty = fmaxf(bi.y, bj.y);
        float rbx = fminf(bi.z, bj.z), rby = fminf(bi.w, bj.w);
        float wx = fmaxf(rbx - ltx, 0.f), wy = fmaxf(rby - lty, 0.f);
        float inter = opaquef(wx * wy);
        float uni = fmaxf(areai + areaj - inter, 1e-12f);
        float iou = inter / uni;
        if ((jbase + k) > i && iou > NMS_THR) word |= (1ull << k);
    }
    mask[(size_t)i * STR + cc] = word;
}

// ---------------- single-wave greedy NMS reduce (v5) ----------------
//  - kept-row propagation: ONE global_load_lds per kept row (whole 640B row ->
//    LDS slot, no VGPR cost), issued inside the decision chain as bits are found;
//    ONE vmcnt(0) wait at next word start, then cheap LDS ORs
//  - diag word: speculative per-lane gather issued one word ahead (full cover)
//  - early exit once total kept >= POST_K
__global__ __launch_bounds__(64) void reduce_kernel(const u64* __restrict__ mask,
                                                    const u64* __restrict__ validm,
                                                    u64* __restrict__ keepw) {
    int lane = threadIdx.x;
    __shared__ __align__(16) u64 prop[NSLOT * 128];  // 63 row slots x 1 KiB

    u64 remv0 = 0ull, remv1 = 0ull, keep0 = 0ull, keep1 = 0ull;
    u64 valid0 = validm[lane];
    bool lo2 = (lane < NW - 64);
    u64 valid1 = lo2 ? validm[64 + lane] : 0ull;
    u32 total = 0;
    int kprev = 0, oflow = -1;

    // prologue: gather word-0 diag (lane b holds mask[b][word 0])
    u64 dnext = mask[(size_t)lane * STR + 0];

    for (int w = 0; w < NW; ++w) {
        // drain prev word's row DMAs (and the diag gather) before LDS reads
        asm volatile("s_waitcnt vmcnt(0)" ::: "memory");
        __builtin_amdgcn_sched_barrier(0);
        u64 dreg = dnext;
        // speculative diag gather for next word (full word of latency cover)
        if (w + 1 < NW)
            dnext = mask[(size_t)((w + 1) * 64 + lane) * STR + (w + 1)];
        // fold previous word's kept rows from LDS into remv (2-way banks, ~free)
        for (int j = 0; j < kprev; ++j) {
            remv0 |= prop[j * 128 + lane];
            if (lo2) remv1 |= prop[j * 128 + 64 + lane];
        }
        if (oflow >= 0) {  // rare: 64th kept row of a word, direct global OR
            const u64* rp = mask + (size_t)oflow * STR;
            remv0 |= rp[lane];
            if (lo2) remv1 |= rp[64 + lane];
            oflow = -1;
        }
        u64 remw, valw;
        if (w < 64) { remw = readlane64(remv0, w); valw = readlane64(valid0, w); }
        else        { remw = readlane64(remv1, w - 64); valw = readlane64(valid1, w - 64); }
        u64 cur = valw & ~remw;            // wave-uniform
        u64 keptw = 0ull;
        int k = 0;
        while (cur) {
            int b = __ffsll(cur) - 1;
            keptw |= (1ull << b);
            // issue row prefetch immediately (latency rides under rest of chain)
            if (k < NSLOT)
                gload_lds16((const char*)(mask + (size_t)((w << 6) + b) * STR) + lane * 16,
                            (void*)(prop + (size_t)k * 128));
            else
                oflow = (w << 6) + b;
            ++k;
            u64 roww = readlane64(dreg, b);  // same-word suppression bits
            cur &= ~(roww | (1ull << b));
        }
        kprev = (k < NSLOT) ? k : NSLOT;
        if (w < 64) { if (lane == w) keep0 |= keptw; }
        else if (lane == w - 64) keep1 |= keptw;
        total += (u32)__popcll(keptw);
        if (total >= POST_K) break;        // output fully determined
    }

    keepw[lane] = keep0;
    keepw[64 + lane] = keep1;
}

// ---------------- scatter kept rows (rank < POST_K); rank computed locally ----------------
__global__ __launch_bounds__(256) void scatter_kernel(const float* __restrict__ rows,
                                                      const u64* __restrict__ keepw,
                                                      float* __restrict__ out) {
    int r = blockIdx.x * 256 + threadIdx.x;
    if (r >= PRE_K) return;
    int w = r >> 6, b = r & 63;
    u64 kw = keepw[w];
    if (!((kw >> b) & 1ull)) return;
    u32 rank = (u32)__popcll(kw & ((1ull << b) - 1ull));
    for (int u = 0; u < w; ++u) rank += (u32)__popcll(keepw[u]);  // L1-cached 640B
    if (rank >= POST_K) return;
    const float* src = rows + (size_t)r * 16;
    float* dst = out + (size_t)rank * 15;
#pragma unroll
    for (int c = 0; c < 15; ++c) dst[c] = src[c];
}

extern "C" void kernel_launch(void* const* d_in, const int* in_sizes, int n_in,
                              void* d_out, int out_size, void* d_ws, size_t ws_size,
                              hipStream_t stream) {
    const float* loc = (const float*)d_in[0];
    const float2* conf2 = (const float2*)d_in[1];
    const float* lmk = (const float*)d_in[2];
    const float* pri = (const float*)d_in[3];
    const int* imw = (const int*)d_in[4];
    const int* imh = (const int*)d_in[5];
    float* out = (float*)d_out;
    char* base = (char*)d_ws;

    // workspace layout (bytes); total 3808896
    u32* hist   = (u32*)(base + 0);         //  65536  [zeroed]
    u32* bfill  = (u32*)(base + 65536);     //  65536  [zeroed]
    u32* bsel   = (u32*)(base + 131072);    //  64     [zeroed]
    u64* validm = (u64*)(base + 131136);    //  1024   [zeroed]
    u64* topk   = (u64*)(base + 132160);    //  40000  [zeroed] -> 172160
    u32* bstart = (u32*)(base + 172160);    //  65536  -> 237696
    u64* cand   = (u64*)(base + 237696);    //  65536  -> 303232
    // rows OVERLAPS bstart+cand: dead once rank_kernel completes; decode_kernel
    // (writer of rows) runs strictly after rank_kernel.
    float* rows = (float*)(base + 172160);  //  320000 -> 492160
    float4* boxes = (float4*)(base + 492160); // 80896 -> 573056
    // keepw OVERLAPS boxes: boxes dead after mask_kernel; reduce writes later.
    u64* keepw  = (u64*)(base + 492160);    //  1024
    u64* mask   = (u64*)(base + 573056);    //  3235840 -> 3808896
    // NOTE: reduce's 1KB row loads: max kept row 4999 -> 4999*640+1024 <= mask size ✓

    hipMemsetAsync(d_ws, 0, 172160, stream);
    hipMemsetAsync(d_out, 0, (size_t)POST_K * 15 * sizeof(float), stream);

    hist_kernel<<<(N_IN + 255) / 256, 256, 0, stream>>>(conf2, hist);
    scan_kernel<<<1, 1024, 0, stream>>>(hist, bsel, bstart);
    compact_kernel<<<(N_IN + 255) / 256, 256, 0, stream>>>(conf2, bsel, bstart, bfill, cand);
    rank_kernel<<<24, 256, 0, stream>>>(cand, bstart, bfill, bsel, topk);
    decode_kernel<<<(PRE_K + 255) / 256, 256, 0, stream>>>(topk, (const float4*)loc,
                                                           (const float4*)pri, lmk, imw, imh,
                                                           (float4*)rows, boxes, validm);
    mask_kernel<<<NW * (NW + 1) / 2, 64, 0, stream>>>(boxes, mask);
    reduce_kernel<<<1, 64, 0, stream>>>(mask, validm, keepw);
    scatter_kernel<<<(PRE_K + 255) / 256, 256, 0, stream>>>(rows, keepw, out);
}